// Round 6
// baseline (34863.864 us; speedup 1.0000x reference)
//
#include <hip/hip_runtime.h>
#include <hip/hip_bf16.h>
#include <stdint.h>

typedef unsigned int u32;
typedef unsigned long long u64;
typedef unsigned short u16;
typedef __bf16 bf16x8 __attribute__((ext_vector_type(8)));
typedef float f32x4 __attribute__((ext_vector_type(4)));

#define LATENT 256
#define TSEQ 128
#define BATCH 512

// d_out float offsets: [len 512*128][type 512*128*32][pos 512*128*4][color 512*128*768]
#define OUT_TYPE_OFF  65536
#define OUT_POS_OFF   2162688
#define OUT_COLOR_OFF 2424832

// workspace byte offsets
#define WS_ARRIVE 0          // 8 groups * 256B (zeroed by memset)
#define WS_AMAX   4096       // 2 * 512 * 4 * u64 = 32768 (zeroed by memset)
#define WS_POS    36864      // 512*4 f32
#define WS_HBUF   45056      // 4 planes (buf0_hi, buf0_lo, buf1_hi, buf1_lo) x 512*256 bf16
#define WS_C0     1093632    // 512*256 f32
#define WS_GXT    1617920    // 32*1024 f32
#define WS_GXC    1748992    // 256*1024 f32
#define WS_GXP    2797568    // 4*1024 f32
#define WS_GB     2813952    // 1024 f32 (b_lstm + b_pos_in@Wx), packed order
#define WS_GBOS   2818048    // 1024 f32 (b_lstm + bos@Wx), packed order
// total 2822144 bytes

#define HPLANE 131072        // u16 elements per h plane (512*256)

__device__ __forceinline__ u16 f2bf(float f) {
  u32 u = __builtin_bit_cast(u32, f);
  u32 r = (u + 0x7FFFu + ((u >> 16) & 1u)) >> 16;
  return (u16)r;
}
__device__ __forceinline__ float bf2f(u16 v) {
  return __builtin_bit_cast(float, ((u32)v) << 16);
}
__device__ __forceinline__ float sigm(float x) { return 1.0f / (1.0f + __expf(-x)); }
__device__ __forceinline__ float tanh_f(float x) { return 2.0f / (1.0f + __expf(-2.0f * x)) - 1.0f; }
// packed gate-col p = w*32 + d*4 + gi  ->  original gate col gi*256 + w*8 + d
__device__ __forceinline__ int gcol_of(int p) {
  int w = p >> 5, c = p & 31;
  return (c & 3) * 256 + w * 8 + (c >> 2);
}
// order-preserving f32 encode in hi32, ~idx in lo32 (ties -> lowest idx wins under max)
__device__ __forceinline__ u64 pack_cand(float v, int idx) {
  u32 b = __builtin_bit_cast(u32, v);
  u32 e = (b & 0x80000000u) ? ~b : (b | 0x80000000u);
  return (((u64)e) << 32) | (u32)(~((u32)idx));
}

// ---------------------------------------------------------------------------
// prep kernel. thread ranges (exact):
//   [0,16384)        h0 (hi/lo planes)   512 rows x 32 slots of 8 dims
//   [16384,32768)    c0 (f32)
//   [32768,40960)    out_length (512 x 16 slots of 8)
//   [40960,45056)    Gx_type  f32 (32 x 128 slots of 8)
//   [45056,77824)    Gx_color f32 (256 x 128)
//   [77824,78336)    Gx_pos   f32 (4 x 128)
//   [78336,80384)    gbias (1024) + gbos (1024)
// grid = 314 blocks x 256
// ---------------------------------------------------------------------------
__global__ void prep_kernel(
    const float* __restrict__ z, const float* __restrict__ bos,
    const float* __restrict__ emb_type, const float* __restrict__ emb_color,
    const float* __restrict__ W_pos_in, const float* __restrict__ b_pos_in,
    const float* __restrict__ Wx, const float* __restrict__ b_lstm,
    const float* __restrict__ Wh0, const float* __restrict__ bh0,
    const float* __restrict__ Wc0, const float* __restrict__ bc0,
    const float* __restrict__ W_len, const float* __restrict__ b_len,
    float* __restrict__ out, char* __restrict__ ws)
{
  const int i = blockIdx.x * 256 + threadIdx.x;
  u16* h0H = (u16*)(ws + WS_HBUF);
  u16* h0L = h0H + HPLANE;
  float* c0b = (float*)(ws + WS_C0);
  float* GxtG = (float*)(ws + WS_GXT);
  float* GxcG = (float*)(ws + WS_GXC);
  float* GxpG = (float*)(ws + WS_GXP);
  float* GbG = (float*)(ws + WS_GB);
  float* GbosG = (float*)(ws + WS_GBOS);

  if (i < 32768) {                       // h0 (first 16384) and c0
    const bool is_c = i >= 16384;
    int j = is_c ? i - 16384 : i;
    int b = j >> 5, d0 = (j & 31) << 3;   // b in [0,512)
    const float* W = is_c ? Wc0 : Wh0;
    const float* bb = is_c ? bc0 : bh0;
    float acc[8];
#pragma unroll
    for (int q = 0; q < 8; ++q) acc[q] = bb[d0 + q];
    const float* zr = z + b * 256;
#pragma unroll 4
    for (int k = 0; k < 256; ++k) {
      float zv = zr[k];
      const float* wr = W + k * 256 + d0;
      float4 w0 = *(const float4*)wr;
      float4 w1 = *(const float4*)(wr + 4);
      acc[0] += zv * w0.x; acc[1] += zv * w0.y; acc[2] += zv * w0.z; acc[3] += zv * w0.w;
      acc[4] += zv * w1.x; acc[5] += zv * w1.y; acc[6] += zv * w1.z; acc[7] += zv * w1.w;
    }
    if (is_c) {
#pragma unroll
      for (int q = 0; q < 8; ++q) c0b[b * 256 + d0 + q] = tanh_f(acc[q]);
    } else {
#pragma unroll
      for (int q = 0; q < 8; ++q) {
        float hv = tanh_f(acc[q]);
        u16 hi = f2bf(hv);
        h0H[b * 256 + d0 + q] = hi;
        h0L[b * 256 + d0 + q] = f2bf(hv - bf2f(hi));
      }
    }
  } else if (i < 40960) {                // out_length = z@W_len + b_len (exact f32)
    int j = i - 32768;
    int b = j >> 4, t0 = (j & 15) << 3;
    float acc[8];
#pragma unroll
    for (int q = 0; q < 8; ++q) acc[q] = b_len[t0 + q];
    const float* zr = z + b * 256;
#pragma unroll 4
    for (int k = 0; k < 256; ++k) {
      float zv = zr[k];
      const float* wr = W_len + k * 128 + t0;
      float4 w0 = *(const float4*)wr;
      float4 w1 = *(const float4*)(wr + 4);
      acc[0] += zv * w0.x; acc[1] += zv * w0.y; acc[2] += zv * w0.z; acc[3] += zv * w0.w;
      acc[4] += zv * w1.x; acc[5] += zv * w1.y; acc[6] += zv * w1.z; acc[7] += zv * w1.w;
    }
#pragma unroll
    for (int q = 0; q < 8; ++q) out[b * 128 + t0 + q] = acc[q];
  } else if (i < 77824) {                // Gx_type (4096 thr) + Gx_color (32768), f32
    int j = i - 40960;
    const bool is_t = j < 4096;
    if (!is_t) j -= 4096;
    const float* E = is_t ? emb_type : emb_color;
    int v = j >> 7, p8 = (j & 127) << 3;
    int wslot = p8 >> 5, d0 = (p8 & 31) >> 2;
    float acc[8] = {0.f,0.f,0.f,0.f,0.f,0.f,0.f,0.f};
    const float* er = E + v * 256;
#pragma unroll 2
    for (int k = 0; k < 256; ++k) {
      float e = er[k];
      const float* row = Wx + k * 1024 + wslot * 8 + d0;
#pragma unroll
      for (int gi = 0; gi < 4; ++gi) {
        float2 w2 = *(const float2*)(row + gi * 256);
        acc[gi] += e * w2.x;
        acc[4 + gi] += e * w2.y;
      }
    }
    float* dst = (is_t ? GxtG : GxcG) + v * 1024 + p8;
#pragma unroll
    for (int q = 0; q < 8; ++q) dst[q] = acc[q];
  } else if (i < 78336) {                // Gx_pos = W_pos_in @ Wx (f32)
    int j = i - 77824;
    int v = j >> 7, p8 = (j & 127) << 3;
    int wslot = p8 >> 5, d0 = (p8 & 31) >> 2;
    float acc[8] = {0.f,0.f,0.f,0.f,0.f,0.f,0.f,0.f};
    const float* er = W_pos_in + v * 256;
#pragma unroll 2
    for (int k = 0; k < 256; ++k) {
      float e = er[k];
      const float* row = Wx + k * 1024 + wslot * 8 + d0;
#pragma unroll
      for (int gi = 0; gi < 4; ++gi) {
        float2 w2 = *(const float2*)(row + gi * 256);
        acc[gi] += e * w2.x;
        acc[4 + gi] += e * w2.y;
      }
    }
    float* dst = GxpG + v * 1024 + p8;
#pragma unroll
    for (int q = 0; q < 8; ++q) dst[q] = acc[q];
  } else if (i < 80384) {                // gbias (1024) + gbos (1024), packed order
    int j = i - 78336;
    bool is_bos = j >= 1024;
    int p = is_bos ? j - 1024 : j;
    int gc = gcol_of(p);
    const float* src = is_bos ? bos : b_pos_in;
    float acc = b_lstm[gc];
#pragma unroll 4
    for (int k = 0; k < 256; ++k) acc += src[k] * Wx[k * 1024 + gc];
    (is_bos ? GbosG : GbG)[p] = acc;
  }
}

// ---------------------------------------------------------------------------
// persistent main kernel: 8 groups x 32 WGs x 1024 thr, 2 group barriers/step
// split-bf16 (hi+lo) MFMA: A@B ~= Ah@Bh + Ah@Bl + Al@Bh  (~1e-6 accuracy)
// ---------------------------------------------------------------------------
__device__ __forceinline__ void group_barrier(u32* arr, u32 target) {
  __threadfence();
  __syncthreads();
  if (threadIdx.x == 0) {
    __hip_atomic_fetch_add(arr, 1u, __ATOMIC_RELAXED, __HIP_MEMORY_SCOPE_AGENT);
    while (__hip_atomic_load(arr, __ATOMIC_RELAXED, __HIP_MEMORY_SCOPE_AGENT) < target) {
      __builtin_amdgcn_s_sleep(2);
    }
  }
  __syncthreads();
  __threadfence();
}

__global__ void __launch_bounds__(1024, 4)
ar_main(const float* __restrict__ Wh,
        const float* __restrict__ W_type, const float* __restrict__ b_type,
        const float* __restrict__ W_pos, const float* __restrict__ b_pos,
        const float* __restrict__ W_color, const float* __restrict__ b_color,
        float* __restrict__ out, char* __restrict__ ws)
{
  const int bid = blockIdx.x;
  const int g = bid & 7;          // group (one XCD, heuristically)
  const int w = bid >> 3;         // WG index in group, 0..31
  const int tid = threadIdx.x;
  const int wave = tid >> 6;
  const int lane = tid & 63;

  u32* arrive = (u32*)(ws + WS_ARRIVE) + g * 64;
  u64* amax = (u64*)(ws + WS_AMAX);
  float* posb = (float*)(ws + WS_POS);
  u16* hbufB = (u16*)(ws + WS_HBUF);
  const float* c0b = (const float*)(ws + WS_C0);
  const float* GxtG = (const float*)(ws + WS_GXT);
  const float* GxcG = (const float*)(ws + WS_GXC);
  const float* GxpG = (const float*)(ws + WS_GXP);
  const float* GbG = (const float*)(ws + WS_GB);
  const float* GbosG = (const float*)(ws + WS_GBOS);

  __shared__ u16 sWhH[8192];      // [32 col][256 k] hi, XOR-swizzled
  __shared__ u16 sWhL[8192];      // lo
  __shared__ u16 sHdH[8192];      // head weights hi (rows >=26 zero), swizzled
  __shared__ u16 sHdL[8192];      // lo
  __shared__ float sGxc[8192];    // [256][32] f32
  __shared__ float sGxt[1024];    // [32][32] f32
  __shared__ float sGxp[128];     // [4][32]
  __shared__ float sGb[32];
  __shared__ float sGbos[32];
  __shared__ float sHbias[32];
  __shared__ float sGx[64 * 33];  // gather-contrib, padded
  __shared__ int sIdx[256];       // [64 rows][4 tables]
  __shared__ float sPos[256];     // [64 rows][4]

  // ---- prologue: split weights hi/lo into LDS, stage tables ----
  {
    int p = tid >> 5, kb = tid & 31;
    int gc = gcol_of(w * 32 + p);
    u32 soff = ((u32)(p * 512 + kb * 16)) ^ ((u32)(p & 7) << 4);
    u16* dH = (u16*)((char*)sWhH + soff);
    u16* dL = (u16*)((char*)sWhL + soff);
#pragma unroll
    for (int q = 0; q < 8; ++q) {
      float wv = Wh[(kb * 8 + q) * 1024 + gc];
      u16 hi = f2bf(wv);
      dH[q] = hi;
      dL[q] = f2bf(wv - bf2f(hi));
    }
    int pc = w * 26 + p;
    const bool hok = (p < 26) && (pc < 804);
    u16* eH = (u16*)((char*)sHdH + soff);
    u16* eL = (u16*)((char*)sHdL + soff);
#pragma unroll
    for (int q = 0; q < 8; ++q) {
      float wv = 0.f;
      int k = kb * 8 + q;
      if (hok)
        wv = (pc < 32) ? W_type[k * 32 + pc]
           : (pc < 36) ? W_pos[k * 4 + (pc - 32)]
                       : W_color[k * 768 + (pc - 36)];
      u16 hi = f2bf(wv);
      eH[q] = hi;
      eL[q] = f2bf(wv - bf2f(hi));
    }
  }
  {
    int v = tid >> 2, c0i = (tid & 3) << 3;
    const float* src = GxcG + (size_t)v * 1024 + w * 32 + c0i;
    *(float4*)(sGxc + v * 32 + c0i) = *(const float4*)src;
    *(float4*)(sGxc + v * 32 + c0i + 4) = *(const float4*)(src + 4);
  }
  if (tid < 128) {
    int v = tid >> 2, c0i = (tid & 3) << 3;
    const float* src = GxtG + (size_t)v * 1024 + w * 32 + c0i;
    *(float4*)(sGxt + v * 32 + c0i) = *(const float4*)src;
    *(float4*)(sGxt + v * 32 + c0i + 4) = *(const float4*)(src + 4);
    sGxp[tid] = GxpG[(tid >> 5) * 1024 + w * 32 + (tid & 31)];
  }
  if (tid < 32) {
    sGb[tid] = GbG[w * 32 + tid];
    sGbos[tid] = GbosG[w * 32 + tid];
    int pc2 = w * 26 + tid;
    float hb = 0.f;
    if (tid < 26 && pc2 < 804)
      hb = (pc2 < 32) ? b_type[pc2] : (pc2 < 36) ? b_pos[pc2 - 32] : b_color[pc2 - 36];
    sHbias[tid] = hb;
  }
  __syncthreads();

  // wave geometry (same formulas serve gate waves 0-7 and head waves 8-15)
  const int mw = wave & 3;                 // M-tile
  const int nw = (wave >> 2) & 1;          // N-tile
  const int colL = (lane & 15) + nw * 16;  // local column 0..31
  const int gi = colL & 3;                 // gate id i,f,g,o
  const int dd = colL >> 2;                // local latent dim 0..7
  const int rquad = (lane >> 4) << 2;      // row quad base within tile

  float c_reg[4] = {0.f, 0.f, 0.f, 0.f};
  if (wave < 8 && gi == 0) {
#pragma unroll
    for (int r = 0; r < 4; ++r)
      c_reg[r] = c0b[(size_t)(g * 64 + mw * 16 + rquad + r) * 256 + w * 8 + dd];
  }

  const u32 xorv = (u32)(colL & 7) << 4;
  const u32 kl = (u32)(lane >> 4) << 4;
  const size_t rowoff = (size_t)(g * 64 + mw * 16 + (lane & 15)) * 256 + ((lane >> 4) << 3);

  for (int s = 0; s < TSEQ; ++s) {
    const u16* hrH = hbufB + (size_t)(2 * (s & 1)) * HPLANE;
    u16* hwH = hbufB + (size_t)(2 * ((s + 1) & 1)) * HPLANE;

    // ---- phase A: gates = h@Wh (split MFMA) + gathered-embedding contribution ----
    f32x4 acc;
    if (wave < 8) {
      const u16* apH = hrH + rowoff;
      const u16* apL = apH + HPLANE;
      f32x4 a0 = {0.f, 0.f, 0.f, 0.f}, a1 = a0, a2 = a0;
#pragma unroll
      for (int k0 = 0; k0 < 256; k0 += 32) {
        uint4 avH = *(const uint4*)(apH + k0);
        uint4 avL = *(const uint4*)(apL + k0);
        u32 boff = (u32)(colL * 512) + (((u32)(k0 * 2) + kl) ^ xorv);
        uint4 bvH = *(const uint4*)((const char*)sWhH + boff);
        uint4 bvL = *(const uint4*)((const char*)sWhL + boff);
        a0 = __builtin_amdgcn_mfma_f32_16x16x32_bf16(
            __builtin_bit_cast(bf16x8, avH), __builtin_bit_cast(bf16x8, bvH), a0, 0, 0, 0);
        a1 = __builtin_amdgcn_mfma_f32_16x16x32_bf16(
            __builtin_bit_cast(bf16x8, avH), __builtin_bit_cast(bf16x8, bvL), a1, 0, 0, 0);
        a2 = __builtin_amdgcn_mfma_f32_16x16x32_bf16(
            __builtin_bit_cast(bf16x8, avL), __builtin_bit_cast(bf16x8, bvH), a2, 0, 0, 0);
      }
#pragma unroll
      for (int r = 0; r < 4; ++r) acc[r] = a0[r] + a1[r] + a2[r];
    } else if (s > 0) {
      int at = tid - 512;
      if (at < 256) {           // decode argmax winners (written last step)
        u64 vv = amax[(size_t)((s + 1) & 1) * 2048 + (size_t)g * 256 + at];
        sIdx[at] = (int)(u32)(~(u32)(vv & 0xFFFFFFFFull));
      } else {
        int a2i = at - 256;
        sPos[a2i] = posb[(size_t)g * 256 + a2i];
      }
    }
    __syncthreads();  // A1: idx/pos staged
    if (wave >= 8) {
      int at = tid - 512;
#pragma unroll
      for (int e = 0; e < 4; ++e) {
        int idx = at + e * 512;
        int row = idx >> 5, c = idx & 31;
        float vgx;
        if (s == 0) {
          vgx = sGbos[c];
        } else {
          const int* ir = sIdx + row * 4;
          const float* pr = sPos + row * 4;
          vgx = sGb[c]
              + sGxt[(ir[0] & 31) * 32 + c]
              + sGxc[(ir[1] & 255) * 32 + c]
              + sGxc[(ir[2] & 255) * 32 + c]
              + sGxc[(ir[3] & 255) * 32 + c]
              + pr[0] * sGxp[c] + pr[1] * sGxp[32 + c]
              + pr[2] * sGxp[64 + c] + pr[3] * sGxp[96 + c];
        }
        sGx[row * 33 + c] = vgx;
      }
    }
    __syncthreads();  // A2: gather contribution ready
    if (wave < 8) {
      float sv[4];
#pragma unroll
      for (int r = 0; r < 4; ++r) {
        float x = acc[r] + sGx[(mw * 16 + rquad + r) * 33 + colL];
        sv[r] = (gi == 2) ? tanh_f(x) : sigm(x);
      }
#pragma unroll
      for (int r = 0; r < 4; ++r) {
        float a0s = sv[r];
        float b1 = __shfl_xor(a0s, 1);
        float c2 = __shfl_xor(a0s, 2);
        float d3 = __shfl_xor(b1, 2);
        if (gi == 0) {  // lane holds sig(i); b1=sig(f); c2=tanh(g); d3=sig(o)
          float cn = b1 * c_reg[r] + a0s * c2;
          c_reg[r] = cn;
          float hn = d3 * tanh_f(cn);
          u16 hi = f2bf(hn);
          size_t ho = (size_t)(g * 64 + mw * 16 + rquad + r) * 256 + (w * 8 + dd);
          hwH[ho] = hi;
          hwH[ho + HPLANE] = f2bf(hn - bf2f(hi));
        }
      }
    }
    group_barrier(arrive, 32u * (u32)(2 * s + 1));  // B1: h_{s+1} visible

    // ---- phase B: head logits, d_out stores, atomicMax argmax ----
    if (wave >= 8) {
      const u16* apH = hwH + rowoff;
      const u16* apL = apH + HPLANE;
      f32x4 h0 = {0.f, 0.f, 0.f, 0.f}, h1 = h0, h2 = h0;
#pragma unroll
      for (int k0 = 0; k0 < 256; k0 += 32) {
        uint4 avH = *(const uint4*)(apH + k0);
        uint4 avL = *(const uint4*)(apL + k0);
        u32 boff = (u32)(colL * 512) + (((u32)(k0 * 2) + kl) ^ xorv);
        uint4 bvH = *(const uint4*)((const char*)sHdH + boff);
        uint4 bvL = *(const uint4*)((const char*)sHdL + boff);
        h0 = __builtin_amdgcn_mfma_f32_16x16x32_bf16(
            __builtin_bit_cast(bf16x8, avH), __builtin_bit_cast(bf16x8, bvH), h0, 0, 0, 0);
        h1 = __builtin_amdgcn_mfma_f32_16x16x32_bf16(
            __builtin_bit_cast(bf16x8, avH), __builtin_bit_cast(bf16x8, bvL), h1, 0, 0, 0);
        h2 = __builtin_amdgcn_mfma_f32_16x16x32_bf16(
            __builtin_bit_cast(bf16x8, avL), __builtin_bit_cast(bf16x8, bvH), h2, 0, 0, 0);
      }
      const int pcol = w * 26 + colL;
      const bool valid = (colL < 26) && (pcol < 804);
      const float bias = sHbias[colL];
      const int rbase = g * 64 + mw * 16 + rquad;
      float v4[4];
#pragma unroll
      for (int r = 0; r < 4; ++r) {
        v4[r] = h0[r] + h1[r] + h2[r] + bias;
        if (valid) {
          int row = rbase + r;
          int o;
          if (pcol < 32) {
            o = OUT_TYPE_OFF + row * 4096 + s * 32 + pcol;
          } else if (pcol < 36) {
            o = OUT_POS_OFF + row * 512 + s * 4 + (pcol - 32);
            posb[row * 4 + (pcol - 32)] = v4[r];
          } else {
            o = OUT_COLOR_OFF + row * 98304 + s * 768 + (pcol - 36);
          }
          out[o] = v4[r];
        }
      }
      int tb = -1, tix = 0;
      if (valid) {
        if (pcol < 32) { tb = 0; tix = pcol; }
        else if (pcol >= 36) { tb = 1 + ((pcol - 36) >> 8); tix = (pcol - 36) & 255; }
      }
      u64* aw = amax + (size_t)(s & 1) * 2048;
#pragma unroll
      for (int utb = 0; utb < 4; ++utb) {
        u64 cand[4];
#pragma unroll
        for (int r = 0; r < 4; ++r)
          cand[r] = (tb == utb) ? pack_cand(v4[r], tix) : 0ull;
#pragma unroll
        for (int sh = 1; sh < 16; sh <<= 1) {
#pragma unroll
          for (int r = 0; r < 4; ++r) {
            u64 o2 = __shfl_xor(cand[r], sh, 16);
            if (o2 > cand[r]) cand[r] = o2;
          }
        }
        if ((lane & 15) == 0) {
#pragma unroll
          for (int r = 0; r < 4; ++r)
            if (cand[r]) atomicMax(&aw[(size_t)(rbase + r) * 4 + utb], cand[r]);
        }
      }
      // reset the buffer consumed this step (2 rows per WG), for reuse next step
      if (wave == 8 && lane < 8) {
        amax[(size_t)((s + 1) & 1) * 2048 + (size_t)(g * 64 + w * 2 + (lane >> 2)) * 4 + (lane & 3)] = 0ull;
      }
    }
    group_barrier(arrive, 32u * (u32)(2 * s + 2));  // B2: logits/argmax visible
  }
}

extern "C" void kernel_launch(void* const* d_in, const int* in_sizes, int n_in,
                              void* d_out, int out_size, void* d_ws, size_t ws_size,
                              hipStream_t stream) {
  const float* z        = (const float*)d_in[0];
  const float* bos      = (const float*)d_in[1];
  const float* emb_type = (const float*)d_in[2];
  const float* emb_color= (const float*)d_in[3];
  const float* W_pos_in = (const float*)d_in[4];
  const float* b_pos_in = (const float*)d_in[5];
  const float* Wx       = (const float*)d_in[6];
  const float* Wh       = (const float*)d_in[7];
  const float* b_lstm   = (const float*)d_in[8];
  const float* Wh0      = (const float*)d_in[9];
  const float* bh0      = (const float*)d_in[10];
  const float* Wc0      = (const float*)d_in[11];
  const float* bc0      = (const float*)d_in[12];
  const float* W_len    = (const float*)d_in[13];
  const float* b_len    = (const float*)d_in[14];
  const float* W_type   = (const float*)d_in[15];
  const float* b_type   = (const float*)d_in[16];
  const float* W_pos    = (const float*)d_in[17];
  const float* b_pos    = (const float*)d_in[18];
  const float* W_color  = (const float*)d_in[19];
  const float* b_color  = (const float*)d_in[20];
  float* out = (float*)d_out;
  char* ws = (char*)d_ws;

  hipMemsetAsync(ws, 0, 36864, stream);  // barrier counters + argmax buffers
  prep_kernel<<<314, 256, 0, stream>>>(z, bos, emb_type, emb_color, W_pos_in, b_pos_in,
      Wx, b_lstm, Wh0, bh0, Wc0, bc0, W_len, b_len, out, ws);
  ar_main<<<256, 1024, 0, stream>>>(Wh, W_type, b_type, W_pos, b_pos, W_color, b_color,
      out, ws);
}